// Round 2
// baseline (21189.986 us; speedup 1.0000x reference)
//
#include <hip/hip_runtime.h>
#include <hip/hip_cooperative_groups.h>

namespace cg = cooperative_groups;

// LSTM: T=512, B=128, I=256, H=1024. Persistent cooperative kernel.
// 256 blocks (1/CU, forced by 110KB LDS) x 512 threads (8 waves).
// Block (rg,cg): rows [rg*64, +64) x gate-cols [cg*8 .. +8) x 4 gates.
// W-slice (32 gate-rows x K=1280) lives in LDS for the whole kernel.
// c-state lives in registers. h ping-pongs as bf16 via ws + grid.sync per step.

#define T_STEPS 512
#define BATCH   128
#define IN_DIM  256
#define HID     1024
#define KDIM    1280
#define NK      20     // KDIM/64
#define NKX     4      // IN_DIM/64

// LDS: Ws[32][1288] bf16 (82,432 B) | As[2][64][72] bf16 (18,432 B) | Gs[64][36] f32 (9,216 B)
#define WS_OFF  0
#define AS_OFF  82432
#define GS_OFF  100864
#define LDS_BYTES 110080

typedef __bf16 bf16x8 __attribute__((ext_vector_type(8)));
typedef float  f32x4  __attribute__((ext_vector_type(4)));

__device__ __forceinline__ unsigned short f2bf(float f) {
  unsigned int u = __builtin_bit_cast(unsigned int, f);
  unsigned int r = (u + 0x7FFFu + ((u >> 16) & 1u)) >> 16;  // RNE
  return (unsigned short)r;
}

__device__ __forceinline__ float sigmoid_fast(float v) {
  v = fminf(fmaxf(v, -30.f), 30.f);
  return 1.f / (1.f + __expf(-v));
}

__device__ __forceinline__ float tanh_fast(float v) {
  v = fminf(fmaxf(v, -15.f), 15.f);
  float e = __expf(-2.f * v);
  return (1.f - e) / (1.f + e);
}

__global__ __launch_bounds__(512, 1) void lstm_persistent(
    const float* __restrict__ x,     // [T][B][I]
    const float* __restrict__ h0,    // [B][H]
    const float* __restrict__ c0,    // [B][H]
    const float* __restrict__ Wih,   // [4H][I]
    const float* __restrict__ Whh,   // [4H][H]
    const float* __restrict__ bih,   // [4H]
    const float* __restrict__ bhh,   // [4H]
    unsigned short* __restrict__ hb, // ws: [2][B*H] bf16 ping-pong
    float* __restrict__ out)         // [T*B*H + B*H + B*H]
{
  extern __shared__ char smem[];
  unsigned short (*Ws)[1288]     = (unsigned short(*)[1288])(smem + WS_OFF);
  unsigned short (*As)[64][72]   = (unsigned short(*)[64][72])(smem + AS_OFF);
  float (*Gs)[36]                = (float(*)[36])(smem + GS_OFF);

  const int tid  = threadIdx.x;
  const int bx   = blockIdx.x;
  const int cgi  = bx & 127;     // gate-col group
  const int rg   = bx >> 7;      // row group
  const int row0 = rg * 64;
  const int j0   = cgi * 8;

  const int wave = tid >> 6;
  const int lane = tid & 63;
  const int col  = lane & 15;
  const int quad = lane >> 4;
  const int mrow = (wave & 3) * 16 + col;   // A row this lane reads
  const int nsel = wave >> 2;               // which 16-col half of B
  const int brow = nsel * 16 + col;         // Ws row for B operand

  // ---- preload W slice (32 gate-rows x 1280) into LDS, cast f32->bf16 ----
  {
    const int w   = tid >> 4;      // 0..31 local gate-row
    const int t16 = tid & 15;
    const int g = w >> 3, jj = w & 7;
    const size_t grow = (size_t)g * HID + j0 + jj;
    const float* wih_r = Wih + grow * IN_DIM;
    const float* whh_r = Whh + grow * HID;
    #pragma unroll
    for (int c = 0; c < 10; ++c) {
      int k = t16 * 80 + c * 8;
      const float* src = (k < IN_DIM) ? (wih_r + k) : (whh_r + (k - IN_DIM));
      float4 f0 = *reinterpret_cast<const float4*>(src);
      float4 f1 = *reinterpret_cast<const float4*>(src + 4);
      ushort4 u0, u1;
      u0.x = f2bf(f0.x); u0.y = f2bf(f0.y); u0.z = f2bf(f0.z); u0.w = f2bf(f0.w);
      u1.x = f2bf(f1.x); u1.y = f2bf(f1.y); u1.z = f2bf(f1.z); u1.w = f2bf(f1.w);
      *reinterpret_cast<ushort4*>(&Ws[w][k])     = u0;
      *reinterpret_cast<ushort4*>(&Ws[w][k + 4]) = u1;
    }
  }

  // ---- per-thread persistent state (epilogue mapping) ----
  const int erow = tid >> 3;            // 0..63
  const int ejj  = tid & 7;             // 0..7
  const size_t eoff = (size_t)(row0 + erow) * HID + (j0 + ejj);
  float c_reg = c0[eoff];
  const float bi = bih[j0 + ejj]           + bhh[j0 + ejj];
  const float bf_ = bih[HID + j0 + ejj]    + bhh[HID + j0 + ejj];
  const float bg = bih[2 * HID + j0 + ejj] + bhh[2 * HID + j0 + ejj];
  const float bo = bih[3 * HID + j0 + ejj] + bhh[3 * HID + j0 + ejj];
  hb[eoff] = f2bf(h0[eoff]);            // publish h0 into ping buffer 0

  // ---- staging map: one 16B chunk / thread / k-tile ----
  const int srow = tid >> 3;            // 0..63
  const int skc  = tid & 7;             // k chunk: elements skc*8..+8
  const float* xbase = x + (size_t)(row0 + srow) * IN_DIM + skc * 8;

  // pipeline hold registers
  float4 fa0, fb0, fa1, fb1;
  uint4  u0v = {0,0,0,0}, u1v = {0,0,0,0};

  // issue x tiles 0,1 for t=0 before the sync (x doesn't depend on h)
  {
    const float* xt = xbase;            // t=0
    fa0 = *reinterpret_cast<const float4*>(xt);
    fb0 = *reinterpret_cast<const float4*>(xt + 4);
    fa1 = *reinterpret_cast<const float4*>(xt + 64);
    fb1 = *reinterpret_cast<const float4*>(xt + 64 + 4);
  }

  cg::this_grid().sync();

  float h_last = 0.f;

  for (int t = 0; t < T_STEPS; ++t) {
    const float* xt = xbase + (size_t)t * BATCH * IN_DIM;
    const unsigned short* hin =
        hb + (size_t)(t & 1) * (BATCH * HID) + (size_t)(row0 + srow) * HID + skc * 8;

    // COMMIT tile 0 (held in set0)
    {
      unsigned short* dst = &As[0][srow][skc * 8];
      ushort4 a, b;
      a.x = f2bf(fa0.x); a.y = f2bf(fa0.y); a.z = f2bf(fa0.z); a.w = f2bf(fa0.w);
      b.x = f2bf(fb0.x); b.y = f2bf(fb0.y); b.z = f2bf(fb0.z); b.w = f2bf(fb0.w);
      *reinterpret_cast<ushort4*>(dst)     = a;
      *reinterpret_cast<ushort4*>(dst + 4) = b;
    }
    __syncthreads();

    f32x4 acc = {0.f, 0.f, 0.f, 0.f};

    #pragma unroll 2
    for (int kt = 0; kt < NK; ++kt) {
      const bool even = ((kt & 1) == 0);
      // ISSUE tile kt+2 into the free hold set
      if (kt + 2 < NK) {
        const int ki = kt + 2;
        if (even) {
          if (ki < NKX) {
            fa0 = *reinterpret_cast<const float4*>(xt + ki * 64);
            fb0 = *reinterpret_cast<const float4*>(xt + ki * 64 + 4);
          } else {
            u0v = *reinterpret_cast<const uint4*>(hin + (ki - NKX) * 64);
          }
        } else {
          if (ki < NKX) {
            fa1 = *reinterpret_cast<const float4*>(xt + ki * 64);
            fb1 = *reinterpret_cast<const float4*>(xt + ki * 64 + 4);
          } else {
            u1v = *reinterpret_cast<const uint4*>(hin + (ki - NKX) * 64);
          }
        }
      }
      // MFMA on As[kt&1], W resident in LDS
      #pragma unroll
      for (int s = 0; s < 2; ++s) {
        bf16x8 a = *reinterpret_cast<const bf16x8*>(&As[kt & 1][mrow][s * 32 + quad * 8]);
        bf16x8 b = *reinterpret_cast<const bf16x8*>(&Ws[brow][kt * 64 + s * 32 + quad * 8]);
        acc = __builtin_amdgcn_mfma_f32_16x16x32_bf16(a, b, acc, 0, 0, 0);
      }
      // COMMIT tile kt+1 from the other hold set
      if (kt + 1 < NK) {
        const int kc = kt + 1;
        unsigned short* dst = &As[kc & 1][srow][skc * 8];
        if (even) {
          if (kc < NKX) {
            ushort4 a, b;
            a.x = f2bf(fa1.x); a.y = f2bf(fa1.y); a.z = f2bf(fa1.z); a.w = f2bf(fa1.w);
            b.x = f2bf(fb1.x); b.y = f2bf(fb1.y); b.z = f2bf(fb1.z); b.w = f2bf(fb1.w);
            *reinterpret_cast<ushort4*>(dst)     = a;
            *reinterpret_cast<ushort4*>(dst + 4) = b;
          } else {
            *reinterpret_cast<uint4*>(dst) = u1v;
          }
        } else {
          if (kc < NKX) {
            ushort4 a, b;
            a.x = f2bf(fa0.x); a.y = f2bf(fa0.y); a.z = f2bf(fa0.z); a.w = f2bf(fa0.w);
            b.x = f2bf(fb0.x); b.y = f2bf(fb0.y); b.z = f2bf(fb0.z); b.w = f2bf(fb0.w);
            *reinterpret_cast<ushort4*>(dst)     = a;
            *reinterpret_cast<ushort4*>(dst + 4) = b;
          } else {
            *reinterpret_cast<uint4*>(dst) = u0v;
          }
        }
      }
      __syncthreads();
    }

    // ---- spill accumulator (C/D: row=quad*4+r, col=lane&15) ----
    #pragma unroll
    for (int r = 0; r < 4; ++r)
      Gs[(wave & 3) * 16 + quad * 4 + r][nsel * 16 + col] = acc[r];
    __syncthreads();

    // ---- epilogue: one (b,j) per thread ----
    float ig = Gs[erow][ejj]      + bi;
    float fg = Gs[erow][8 + ejj]  + bf_;
    float gg = Gs[erow][16 + ejj] + bg;
    float og = Gs[erow][24 + ejj] + bo;
    ig = sigmoid_fast(ig);
    fg = sigmoid_fast(fg);
    og = sigmoid_fast(og);
    gg = tanh_fast(gg);
    c_reg = fg * c_reg + ig * gg;
    float hval = og * tanh_fast(c_reg);
    out[(size_t)t * BATCH * HID + eoff] = hval;
    hb[(size_t)((t + 1) & 1) * (BATCH * HID) + eoff] = f2bf(hval);
    h_last = hval;

    // issue next step's x tiles 0,1 before the sync (covers sync latency)
    if (t + 1 < T_STEPS) {
      const float* xn = xbase + (size_t)(t + 1) * BATCH * IN_DIM;
      fa0 = *reinterpret_cast<const float4*>(xn);
      fb0 = *reinterpret_cast<const float4*>(xn + 4);
      fa1 = *reinterpret_cast<const float4*>(xn + 64);
      fb1 = *reinterpret_cast<const float4*>(xn + 64 + 4);
    }

    cg::this_grid().sync();
  }

  // ---- finals ----
  const size_t fin = (size_t)T_STEPS * BATCH * HID;
  out[fin + eoff] = h_last;                 // h_final
  out[fin + BATCH * HID + eoff] = c_reg;    // c_final
}

extern "C" void kernel_launch(void* const* d_in, const int* in_sizes, int n_in,
                              void* d_out, int out_size, void* d_ws, size_t ws_size,
                              hipStream_t stream) {
  const float* x   = (const float*)d_in[0];
  const float* h0  = (const float*)d_in[1];
  const float* c0  = (const float*)d_in[2];
  const float* Wih = (const float*)d_in[3];
  const float* Whh = (const float*)d_in[4];
  const float* bih = (const float*)d_in[5];
  const float* bhh = (const float*)d_in[6];
  float* out = (float*)d_out;
  unsigned short* hb = (unsigned short*)d_ws;   // 2 * 128*1024 bf16 = 512 KB

  hipFuncSetAttribute((const void*)lstm_persistent,
                      hipFuncAttributeMaxDynamicSharedMemorySize, LDS_BYTES);

  void* args[] = {(void*)&x, (void*)&h0, (void*)&c0, (void*)&Wih, (void*)&Whh,
                  (void*)&bih, (void*)&bhh, (void*)&hb, (void*)&out};
  hipLaunchCooperativeKernel((void*)lstm_persistent, dim3(256), dim3(512),
                             args, LDS_BYTES, stream);
}